// Round 5
// baseline (1626.514 us; speedup 1.0000x reference)
//
#include <hip/hip_runtime.h>
#include <hip/hip_bf16.h>
#include <math.h>

using bf16 = __hip_bfloat16;
typedef __bf16 bfv8 __attribute__((ext_vector_type(8)));
typedef float f32x4 __attribute__((ext_vector_type(4)));

__device__ __forceinline__ f32x4 mfma16(bfv8 a, bfv8 b, f32x4 c) {
    return __builtin_amdgcn_mfma_f32_16x16x32_bf16(a, b, c, 0, 0, 0);
}

__device__ __forceinline__ void gload_lds16(const void* g, void* l) {
    __builtin_amdgcn_global_load_lds(
        (const __attribute__((address_space(1))) void*)g,
        (__attribute__((address_space(3))) void*)l, 16, 0, 0);
}

// ---------------------------------------------------------------- cvt f32->bf16
__global__ void cvt_kernel(const float* __restrict__ in, bf16* __restrict__ out, long n8) {
    long u = (long)blockIdx.x * 256 + threadIdx.x;
    if (u >= n8) return;
    const float4* p = (const float4*)in + u * 2;
    float4 a = p[0], b = p[1];
    bf16 t8[8] = { __float2bfloat16(a.x), __float2bfloat16(a.y), __float2bfloat16(a.z), __float2bfloat16(a.w),
                   __float2bfloat16(b.x), __float2bfloat16(b.y), __float2bfloat16(b.z), __float2bfloat16(b.w) };
    *(int4*)(out + u * 8) = *(const int4*)t8;
}

// ---------------------------------------------------------------- layernorm (D=4096), fp32 in -> bf16 out
__global__ void layernorm_kernel(const float* __restrict__ x, const float* __restrict__ gw,
                                 const float* __restrict__ gb, bf16* __restrict__ out)
{
    const int D = 4096;
    int row = blockIdx.x, t = threadIdx.x;
    const float4* xr = (const float4*)(x + (size_t)row * D);
    float4 v[4];
    float s1 = 0.f, s2 = 0.f;
#pragma unroll
    for (int j = 0; j < 4; ++j) {
        v[j] = xr[t + j * 256];
        s1 += v[j].x + v[j].y + v[j].z + v[j].w;
        s2 += v[j].x * v[j].x + v[j].y * v[j].y + v[j].z * v[j].z + v[j].w * v[j].w;
    }
#pragma unroll
    for (int d = 1; d < 64; d <<= 1) { s1 += __shfl_xor(s1, d); s2 += __shfl_xor(s2, d); }
    __shared__ float red[8];
    int wave = t >> 6, lane = t & 63;
    if (lane == 0) { red[wave] = s1; red[4 + wave] = s2; }
    __syncthreads();
    s1 = red[0] + red[1] + red[2] + red[3];
    s2 = red[4] + red[5] + red[6] + red[7];
    float mu = s1 * (1.f / 4096.f);
    float var = s2 * (1.f / 4096.f) - mu * mu;
    float rs = rsqrtf(var + 1e-5f);
    bf16* orow = out + (size_t)row * D;
#pragma unroll
    for (int j = 0; j < 4; ++j) {
        int base = (t + j * 256) * 4;
        float xs[4] = { v[j].x, v[j].y, v[j].z, v[j].w };
        bf16 o4[4];
#pragma unroll
        for (int c = 0; c < 4; ++c)
            o4[c] = __float2bfloat16((xs[c] - mu) * rs * gw[base + c] + gb[base + c]);
        *(int2*)(orow + base) = *(const int2*)o4;
    }
}

// ---------------------------------------------------------------- RoPE in-place on bf16 [rows, nheads*128]
__global__ void rope_kernel(bf16* __restrict__ x, int nheads, int seqlen, long total) {
    long idx = (long)blockIdx.x * 256 + threadIdx.x;
    if (idx >= total) return;
    int j = (int)(idx & 63);
    long t2 = idx >> 6;
    int h = (int)(t2 % nheads);
    long row = t2 / nheads;
    int pos = (int)(row % seqlen);
    float inv = exp2f(-(float)j * 0.20762050593046015f);  // log2(10000)/64
    float ang = (float)pos * inv;
    float s, c;
    sincosf(ang, &s, &c);
    bf16* p = x + row * ((long)nheads * 128) + (long)h * 128 + j;
    float x0 = __bfloat162float(p[0]);
    float x1 = __bfloat162float(p[64]);
    p[0]  = __float2bfloat16(x0 * c - x1 * s);
    p[64] = __float2bfloat16(x1 * c + x0 * s);
}

// ---------------------------------------------------------------- 8-phase pipelined GEMM
// C[M,N] = A[M,K] x W[N,K]^T. BM=256 fixed, BK=64, 512 thr = 8 waves (2M x 4N).
// Per-wave output 128 x BN/4. 2 LDS buffers (even tiles buf0, odd buf1); iteration
// computes tiles e=2i (buf0) and o=2i+1 (buf1) in 8 quadrant-phases of 4x(NFH)x2 MFMA.
// Quadrant order (mh,nh): 00,01,11,10 -> ds_reads per phase 12/4/8/0 (BN=256).
// Stage slots: ph4 stages e+2 -> buf0 (all reads of buf0 done at ph3 barrier);
// ph8 stages o+2 -> buf1. Counted vmcnt(SLD) at ph4 (gates o) and ph8 (gates e+2);
// never 0 mid-loop. Steady state: 2*SLD loads in flight, vmcnt retires oldest SLD.
// LDS rows 128B; swizzle byte ^= ((row&7)<<4): 16-lane column reads -> 2 lanes/16B slot
// (free 2-way). Inverse swizzle on global_load_lds source, forward on ds_read (rule 21).
// MODE 0: bf16; 1: silu->bf16; 2: *aux(bf16)->bf16; 3: +aux(f32)->f32
template<int BN, int MODE, bool DUAL, int CM, int CN, int XN>
__global__ __launch_bounds__(512, 1) void gemm8(
        const bf16* __restrict__ A, const bf16* __restrict__ W, const bf16* __restrict__ W2,
        void* __restrict__ Cout, void* __restrict__ Cout2, const void* __restrict__ aux,
        int M, int N, int K, int Nsplit)
{
    constexpr int NFH = BN / 128;         // n-frags per quadrant (2 or 1)
    constexpr int ABY = 256 * 128;        // A tile bytes (256 rows x 128B)
    constexpr int BBY = BN * 128;         // B tile bytes
    constexpr int BLD = BN / 64;          // B loads per thread per tile
    constexpr int SLD = 4 + BLD;          // total loads per thread per K-tile
    __shared__ alignas(16) char lds8[2][ABY + BBY];

    const int t = threadIdx.x;
    const int wid = t >> 6, lane = t & 63;
    const int lr = lane & 15, lg = lane >> 4;
    const int wr = wid >> 2, wc = wid & 3;
    // 2D-chunked XCD mapping (verified r4: 5x FETCH reduction)
    const int bid = blockIdx.x;
    const int xcd = bid & 7, slot = bid >> 3;
    const int sm = slot / CN, sn = slot % CN;
    const int xm = xcd / XN, xn = xcd % XN;
    const int bm = (xm * CM + sm) * 256;
    const int bn = (xn * CN + sn) * BN;

    auto stage = [&](int kt, int b) {
        const int k0 = kt * 64;
        char* base = &lds8[b][0];
#pragma unroll
        for (int c = 0; c < 4; ++c) {
            int Wb = (t + c * 512) * 16;
            int L = Wb ^ (((Wb >> 7) & 7) << 4);
            gload_lds16(A + (size_t)(bm + (L >> 7)) * K + k0 + ((L & 127) >> 1), base + Wb);
        }
#pragma unroll
        for (int c = 0; c < BLD; ++c) {
            int Wb = (t + c * 512) * 16;
            int L = Wb ^ (((Wb >> 7) & 7) << 4);
            const bf16* src;
            if constexpr (DUAL) {
                int nr = bn + (L >> 7);
                src = (nr >= Nsplit) ? W2 + (size_t)(nr - Nsplit) * K + k0 + ((L & 127) >> 1)
                                     : W  + (size_t)nr * K + k0 + ((L & 127) >> 1);
            } else {
                src = W + (size_t)(bn + (L >> 7)) * K + k0 + ((L & 127) >> 1);
            }
            gload_lds16(src, base + ABY + Wb);
        }
    };

    const f32x4 zero4 = { 0.f, 0.f, 0.f, 0.f };
    f32x4 acc[8][2 * NFH];
#pragma unroll
    for (int m = 0; m < 8; ++m)
#pragma unroll
        for (int n = 0; n < 2 * NFH; ++n) acc[m][n] = zero4;

    bfv8 af[4][2], bfr[2][NFH][2];

#define LOADA(B, MH) do {                                                     \
    const char* _ba = &lds8[B][0];                                            \
    _Pragma("unroll") for (int m = 0; m < 4; ++m)                             \
    _Pragma("unroll") for (int ks = 0; ks < 2; ++ks) {                        \
        int row = wr * 128 + (MH) * 64 + m * 16 + lr;                         \
        int U = row * 128 + ks * 64 + lg * 16;                                \
        af[m][ks] = *(const bfv8*)(_ba + (U ^ ((row & 7) << 4)));             \
    } } while (0)

#define LOADB(B, NH) do {                                                     \
    const char* _bb = &lds8[B][ABY];                                          \
    _Pragma("unroll") for (int n = 0; n < NFH; ++n)                           \
    _Pragma("unroll") for (int ks = 0; ks < 2; ++ks) {                        \
        int row = wc * (BN / 4) + (NH) * (BN / 8) + n * 16 + lr;              \
        int U = row * 128 + ks * 64 + lg * 16;                                \
        bfr[NH][n][ks] = *(const bfv8*)(_bb + (U ^ ((row & 7) << 4)));        \
    } } while (0)

#define MFMAQ(MH, NH) do {                                                    \
    _Pragma("unroll") for (int m = 0; m < 4; ++m)                             \
    _Pragma("unroll") for (int n = 0; n < NFH; ++n) {                         \
        acc[(MH)*4+m][(NH)*NFH+n] = mfma16(af[m][0], bfr[NH][n][0], acc[(MH)*4+m][(NH)*NFH+n]); \
        acc[(MH)*4+m][(NH)*NFH+n] = mfma16(af[m][1], bfr[NH][n][1], acc[(MH)*4+m][(NH)*NFH+n]); \
    } } while (0)

#define PH_TOP() do { __builtin_amdgcn_sched_barrier(0); __builtin_amdgcn_s_barrier();       \
    asm volatile("s_waitcnt lgkmcnt(0)" ::: "memory"); __builtin_amdgcn_sched_barrier(0);    \
    __builtin_amdgcn_s_setprio(1); } while (0)

#define PH_END() do { __builtin_amdgcn_s_setprio(0); __builtin_amdgcn_sched_barrier(0);      \
    __builtin_amdgcn_s_barrier(); } while (0)

#define VM_PRE() do { if constexpr (SLD == 8) asm volatile("s_waitcnt vmcnt(8)" ::: "memory"); \
                      else asm volatile("s_waitcnt vmcnt(6)" ::: "memory"); } while (0)

    const int T = K >> 6;        // K-tiles of 64
    const int T2 = T >> 1;       // iterations (2 tiles each)

    // prologue: tile0 -> buf0, tile1 -> buf1; gate tile0, leave tile1 in flight
    stage(0, 0);
    stage(1, 1);
    VM_PRE();
    __builtin_amdgcn_sched_barrier(0);
    __builtin_amdgcn_s_barrier();

    for (int tt = 0; tt < T2; ++tt) {
        const bool pre = (tt + 1 < T2);
        // ---------------- tile e = 2tt (buf0)
        LOADA(0, 0); LOADB(0, 0);                 // ph1: q00
        PH_TOP(); MFMAQ(0, 0); PH_END();
        LOADB(0, 1);                              // ph2: q01
        PH_TOP(); MFMAQ(0, 1); PH_END();
        LOADA(0, 1);                              // ph3: q11
        PH_TOP(); MFMAQ(1, 1); PH_END();
        if (pre) stage(2 * tt + 2, 0);            // ph4: q10 + stage e+2
        PH_TOP(); MFMAQ(1, 0);
        __builtin_amdgcn_s_setprio(0);
        if (pre) { VM_PRE(); } else { asm volatile("s_waitcnt vmcnt(0)" ::: "memory"); }
        __builtin_amdgcn_sched_barrier(0);
        __builtin_amdgcn_s_barrier();
        // ---------------- tile o = 2tt+1 (buf1)
        LOADA(1, 0); LOADB(1, 0);                 // ph5: q00
        PH_TOP(); MFMAQ(0, 0); PH_END();
        LOADB(1, 1);                              // ph6: q01
        PH_TOP(); MFMAQ(0, 1); PH_END();
        LOADA(1, 1);                              // ph7: q11
        PH_TOP(); MFMAQ(1, 1); PH_END();
        if (pre) stage(2 * tt + 3, 1);            // ph8: q10 + stage o+2
        PH_TOP(); MFMAQ(1, 0);
        __builtin_amdgcn_s_setprio(0);
        if (pre) { VM_PRE(); }
        __builtin_amdgcn_sched_barrier(0);
        __builtin_amdgcn_s_barrier();
    }

#undef LOADA
#undef LOADB
#undef MFMAQ
#undef PH_TOP
#undef PH_END
#undef VM_PRE

    const int r0 = bm + wr * 128, c0 = bn + wc * (BN / 4);
#pragma unroll
    for (int mg = 0; mg < 8; ++mg)
#pragma unroll
        for (int ng = 0; ng < 2 * NFH; ++ng)
#pragma unroll
            for (int i = 0; i < 4; ++i) {
                int r = r0 + mg * 16 + lg * 4 + i;
                int c = c0 + ng * 16 + lr;
                float a = acc[mg][ng][i];
                if constexpr (DUAL) {
                    if (c < Nsplit) ((bf16*)Cout)[(size_t)r * Nsplit + c] = __float2bfloat16(a);
                    else ((bf16*)Cout2)[(size_t)r * (N - Nsplit) + (c - Nsplit)] = __float2bfloat16(a);
                } else {
                    size_t idx = (size_t)r * N + c;
                    if constexpr (MODE == 0) {
                        ((bf16*)Cout)[idx] = __float2bfloat16(a);
                    } else if constexpr (MODE == 1) {
                        a = a / (1.f + expf(-a));
                        ((bf16*)Cout)[idx] = __float2bfloat16(a);
                    } else if constexpr (MODE == 2) {
                        a *= __bfloat162float(((const bf16*)aux)[idx]);
                        ((bf16*)Cout)[idx] = __float2bfloat16(a);
                    } else {
                        ((float*)Cout)[idx] = a + ((const float*)aux)[idx];
                    }
                }
            }
}

// ---------------------------------------------------------------- V transpose: vb[(b*2048+kv)][1024] -> vt[(b*1024+col)][2048]
__global__ void transpose_v(const bf16* __restrict__ vb, bf16* __restrict__ vt) {
    __shared__ bf16 tile[64][68];
    int kv0 = blockIdx.x * 64, c0 = blockIdx.y * 64, b = blockIdx.z;
    int t = threadIdx.x;
    int cr = t & 15, rr = t >> 4;
#pragma unroll
    for (int j = 0; j < 4; ++j) {
        int r = rr + j * 16;
        *(int2*)&tile[r][cr * 4] = *(const int2*)&vb[(size_t)(b * 2048 + kv0 + r) * 1024 + c0 + cr * 4];
    }
    __syncthreads();
#pragma unroll
    for (int j = 0; j < 4; ++j) {
        int cc = rr + j * 16;
        bf16 tmp[4];
#pragma unroll
        for (int q = 0; q < 4; ++q) tmp[q] = tile[cr * 4 + q][cc];
        *(int2*)&vt[(size_t)(b * 1024 + c0 + cc) * 2048 + kv0 + cr * 4] = *(const int2*)tmp;
    }
}

// ---------------------------------------------------------------- flash attention v2 (GQA 32q/8kv, HD=128)
__global__ __launch_bounds__(256) void attn_kernel(
    const bf16* __restrict__ Q, const bf16* __restrict__ Kb, const bf16* __restrict__ Vt,
    const float* __restrict__ mask, bf16* __restrict__ O)
{
    const int QL_ = 1024, KVL_ = 2048;
    const float scale = 0.08838834764831845f;  // 1/sqrt(128)
    int qt = blockIdx.x, h = blockIdx.y, b = blockIdx.z;
    int t = threadIdx.x, wave = t >> 6, lane = t & 63;
    int lr = lane & 15, lg = lane >> 4;
    int g = h >> 2;
    __shared__ bf16 Ksm[64 * 128];     // [kv][d], 256B rows, swizzled
    __shared__ bf16 Vsm[128 * 64];     // [d][kv], 128B rows, swizzled
    __shared__ bf16 Psm[4][16 * 72];   // per-wave P [q][kv], stride 72
    int q0 = qt * 64 + wave * 16;

    const bf16* qptr = Q + (size_t)(b * QL_ + q0 + lr) * 4096 + h * 128;
    bfv8 qf[4];
#pragma unroll
    for (int kc = 0; kc < 4; ++kc) qf[kc] = *(const bfv8*)(qptr + kc * 32 + lg * 8);

    const f32x4 zero4 = { 0.f, 0.f, 0.f, 0.f };
    f32x4 accO[8];
#pragma unroll
    for (int dt = 0; dt < 8; ++dt) accO[dt] = zero4;
    float mrow[4] = { -1e30f, -1e30f, -1e30f, -1e30f };
    float lrow[4] = { 0.f, 0.f, 0.f, 0.f };

    for (int kv0 = 0; kv0 < KVL_; kv0 += 64) {
#pragma unroll
        for (int p2 = 0; p2 < 4; ++p2) {
            int Wb = (p2 * 256 + t) * 16;
            int row = Wb >> 8;
            int col = ((Wb & 255) ^ ((row & 7) << 4)) >> 1;
            gload_lds16(Kb + (size_t)(b * KVL_ + kv0 + row) * 1024 + g * 128 + col,
                        (char*)Ksm + Wb);
        }
#pragma unroll
        for (int p2 = 0; p2 < 4; ++p2) {
            int Wb = (p2 * 256 + t) * 16;
            int row = Wb >> 7;
            int col = ((Wb & 127) ^ ((row & 7) << 4)) >> 1;
            gload_lds16(Vt + (size_t)(b * 1024 + g * 128 + row) * 2048 + kv0 + col,
                        (char*)Vsm + Wb);
        }
        __syncthreads();

        f32x4 s[4];
#pragma unroll
        for (int ct = 0; ct < 4; ++ct) {
            s[ct] = zero4;
#pragma unroll
            for (int kc = 0; kc < 4; ++kc) {
                int row = ct * 16 + lr;
                int U = row * 256 + kc * 64 + lg * 16;
                bfv8 kf = *(const bfv8*)((const char*)Ksm + (U ^ ((row & 7) << 4)));
                s[ct] = mfma16(qf[kc], kf, s[ct]);
            }
            float mv = mask[(size_t)b * KVL_ + kv0 + ct * 16 + lr];
            mv = (mv != 0.f) ? 1.f : 0.f;
#pragma unroll
            for (int i = 0; i < 4; ++i) s[ct][i] = s[ct][i] * scale + mv;
        }

        float rmx[4], mnew[4], corr[4], psum[4];
#pragma unroll
        for (int i = 0; i < 4; ++i) {
            rmx[i] = fmaxf(fmaxf(s[0][i], s[1][i]), fmaxf(s[2][i], s[3][i]));
#pragma unroll
            for (int d = 1; d < 16; d <<= 1) rmx[i] = fmaxf(rmx[i], __shfl_xor(rmx[i], d));
            mnew[i] = fmaxf(mrow[i], rmx[i]);
            corr[i] = expf(mrow[i] - mnew[i]);
            psum[i] = 0.f;
        }
#pragma unroll
        for (int ct = 0; ct < 4; ++ct)
#pragma unroll
            for (int i = 0; i < 4; ++i) {
                float pv = expf(s[ct][i] - mnew[i]);
                psum[i] += pv;
                Psm[wave][(lg * 4 + i) * 72 + ct * 16 + lr] = __float2bfloat16(pv);
            }
#pragma unroll
        for (int i = 0; i < 4; ++i) {
#pragma unroll
            for (int d = 1; d < 16; d <<= 1) psum[i] += __shfl_xor(psum[i], d);
            lrow[i] = lrow[i] * corr[i] + psum[i];
            mrow[i] = mnew[i];
        }
#pragma unroll
        for (int dt = 0; dt < 8; ++dt)
#pragma unroll
            for (int i = 0; i < 4; ++i) accO[dt][i] *= corr[i];
        __syncthreads();

        bfv8 pf0 = *(const bfv8*)&Psm[wave][lr * 72 + 0 * 32 + lg * 8];
        bfv8 pf1 = *(const bfv8*)&Psm[wave][lr * 72 + 1 * 32 + lg * 8];
#pragma unroll
        for (int dt = 0; dt < 8; ++dt) {
            int row = dt * 16 + lr;
            int U0 = row * 128 + 0 * 64 + lg * 16;
            int U1 = row * 128 + 1 * 64 + lg * 16;
            bfv8 vf0 = *(const bfv8*)((const char*)Vsm + (U0 ^ ((row & 7) << 4)));
            bfv8 vf1 = *(const bfv8*)((const char*)Vsm + (U1 ^ ((row & 7) << 4)));
            accO[dt] = mfma16(pf0, vf0, accO[dt]);
            accO[dt] = mfma16(pf1, vf1, accO[dt]);
        }
        __syncthreads();
    }

    float invl[4];
#pragma unroll
    for (int i = 0; i < 4; ++i) invl[i] = 1.f / lrow[i];
#pragma unroll
    for (int dt = 0; dt < 8; ++dt)
#pragma unroll
        for (int i = 0; i < 4; ++i)
            O[(size_t)(b * QL_ + q0 + lg * 4 + i) * 4096 + h * 128 + dt * 16 + lr] =
                __float2bfloat16(accO[dt][i] * invl[i]);
}

// ---------------------------------------------------------------- launch
extern "C" void kernel_launch(void* const* d_in, const int* in_sizes, int n_in,
                              void* d_out, int out_size, void* d_ws, size_t ws_size,
                              hipStream_t stream) {
    const float* hidden = (const float*)d_in[0];
    const float* enc    = (const float*)d_in[1];
    const float* mask   = (const float*)d_in[2];
    const float* ln1w   = (const float*)d_in[3];
    const float* ln1b   = (const float*)d_in[4];
    const float* qw     = (const float*)d_in[5];
    const float* kw     = (const float*)d_in[6];
    const float* vw     = (const float*)d_in[7];
    const float* ow     = (const float*)d_in[8];
    const float* ln2w   = (const float*)d_in[9];
    const float* ln2b   = (const float*)d_in[10];
    const float* gatew  = (const float*)d_in[11];
    const float* upw    = (const float*)d_in[12];
    const float* downw  = (const float*)d_in[13];
    float* out = (float*)d_out;

    char* ws = (char*)d_ws;
    bf16*  wbuf  = (bf16*)(ws);                       // 134,217,728 B
    bf16*  wbuf2 = (bf16*)(ws + 8388608);             // second half for kv (kw 8MB, vw 8MB)
    bf16*  h1    = (bf16*)(ws + 134217728);           // 16,777,216
    bf16*  encb  = (bf16*)(ws + 150994944);           // 33,554,432
    bf16*  qb    = (bf16*)(ws + 184549376);           // 16,777,216
    bf16*  kb    = (bf16*)(ws + 201326592);           // 8,388,608
    bf16*  vb    = (bf16*)(ws + 209715200);           // 8,388,608
    bf16*  attno = (bf16*)(ws + 218103808);           // 16,777,216
    float* h2    = (float*)(ws + 234881024);          // 33,554,432 (vt aliases pre-o-proj)
    bf16*  vt    = (bf16*)(ws + 234881024);           // 8,388,608
    bf16*  h2n   = (bf16*)(ws + 268435456);           // 16,777,216
    bf16*  g1    = (bf16*)(ws + 285212672);           // 67,108,864

    auto cvt = [&](const float* src, bf16* dst, long n) {
        cvt_kernel<<<(int)(n / 2048), 256, 0, stream>>>(src, dst, n / 8);
    };

    // encoder hidden -> bf16; LN1(hidden) -> bf16
    cvt(enc, encb, 16777216L);
    layernorm_kernel<<<2048, 256, 0, stream>>>(hidden, ln1w, ln1b, h1);

    // Q = h1 x qw^T [2048, 4096]: tiles 8m x 32n, XCD grid 1x8, chunk 8x4
    cvt(qw, wbuf, 16777216L);
    gemm8<128, 0, false, 8, 4, 8><<<256, 512, 0, stream>>>(
        h1, wbuf, nullptr, qb, nullptr, nullptr, 2048, 4096, 4096, 0);
    rope_kernel<<<16384, 256, 0, stream>>>(qb, 32, 1024, 2048L * 32 * 64);

    // K,V fused: [4096, 2048]: tiles 16m x 16n, XCD grid 2x4, chunk 8x4
    cvt(kw, wbuf, 4194304L);
    cvt(vw, wbuf2, 4194304L);
    gemm8<128, 0, true, 8, 4, 4><<<256, 512, 0, stream>>>(
        encb, wbuf, wbuf2, kb, vb, nullptr, 4096, 2048, 4096, 1024);
    rope_kernel<<<8192, 256, 0, stream>>>(kb, 8, 2048, 4096L * 8 * 64);
    transpose_v<<<dim3(32, 16, 2), 256, 0, stream>>>(vb, vt);

    // attention
    attn_kernel<<<dim3(16, 32, 2), 256, 0, stream>>>(qb, kb, vt, mask, attno);

    // h2 = hidden + attno x ow^T (fp32)
    cvt(ow, wbuf, 16777216L);
    gemm8<128, 3, false, 8, 4, 8><<<256, 512, 0, stream>>>(
        attno, wbuf, nullptr, h2, nullptr, hidden, 2048, 4096, 4096, 0);

    // LN2 -> bf16
    layernorm_kernel<<<2048, 256, 0, stream>>>(h2, ln2w, ln2b, h2n);

    // g1 = silu(h2n x gatew^T); g1 *= h2n x upw^T: tiles 8m x 64n, XCD grid 1x8, chunk 8x8
    cvt(gatew, wbuf, 67108864L);
    gemm8<256, 1, false, 8, 8, 8><<<512, 512, 0, stream>>>(
        h2n, wbuf, nullptr, g1, nullptr, nullptr, 2048, 16384, 4096, 0);
    cvt(upw, wbuf, 67108864L);
    gemm8<256, 2, false, 8, 8, 8><<<512, 512, 0, stream>>>(
        h2n, wbuf, nullptr, g1, nullptr, g1, 2048, 16384, 4096, 0);

    // out = h2 + g1 x downw^T (fp32): tiles 8m x 32n, chunk 8x4
    cvt(downw, wbuf, 67108864L);
    gemm8<128, 3, false, 8, 4, 8><<<256, 512, 0, stream>>>(
        g1, wbuf, nullptr, out, nullptr, h2, 2048, 4096, 16384, 0);
}

// Round 8
// 1489.825 us; speedup vs baseline: 1.0917x; 1.0917x over previous
//
#include <hip/hip_runtime.h>
#include <hip/hip_bf16.h>
#include <math.h>

using bf16 = __hip_bfloat16;
typedef __bf16 bfv8 __attribute__((ext_vector_type(8)));
typedef float f32x4 __attribute__((ext_vector_type(4)));

__device__ __forceinline__ f32x4 mfma16(bfv8 a, bfv8 b, f32x4 c) {
    return __builtin_amdgcn_mfma_f32_16x16x32_bf16(a, b, c, 0, 0, 0);
}

__device__ __forceinline__ void gload_lds16(const void* g, void* l) {
    __builtin_amdgcn_global_load_lds(
        (const __attribute__((address_space(1))) void*)g,
        (__attribute__((address_space(3))) void*)l, 16, 0, 0);
}

// ---------------------------------------------------------------- cvt f32->bf16
__global__ void cvt_kernel(const float* __restrict__ in, bf16* __restrict__ out, long n8) {
    long u = (long)blockIdx.x * 256 + threadIdx.x;
    if (u >= n8) return;
    const float4* p = (const float4*)in + u * 2;
    float4 a = p[0], b = p[1];
    bf16 t8[8] = { __float2bfloat16(a.x), __float2bfloat16(a.y), __float2bfloat16(a.z), __float2bfloat16(a.w),
                   __float2bfloat16(b.x), __float2bfloat16(b.y), __float2bfloat16(b.z), __float2bfloat16(b.w) };
    *(int4*)(out + u * 8) = *(const int4*)t8;
}

// ---------------------------------------------------------------- layernorm (D=4096), fp32 in -> bf16 out
__global__ void layernorm_kernel(const float* __restrict__ x, const float* __restrict__ gw,
                                 const float* __restrict__ gb, bf16* __restrict__ out)
{
    const int D = 4096;
    int row = blockIdx.x, t = threadIdx.x;
    const float4* xr = (const float4*)(x + (size_t)row * D);
    float4 v[4];
    float s1 = 0.f, s2 = 0.f;
#pragma unroll
    for (int j = 0; j < 4; ++j) {
        v[j] = xr[t + j * 256];
        s1 += v[j].x + v[j].y + v[j].z + v[j].w;
        s2 += v[j].x * v[j].x + v[j].y * v[j].y + v[j].z * v[j].z + v[j].w * v[j].w;
    }
#pragma unroll
    for (int d = 1; d < 64; d <<= 1) { s1 += __shfl_xor(s1, d); s2 += __shfl_xor(s2, d); }
    __shared__ float red[8];
    int wave = t >> 6, lane = t & 63;
    if (lane == 0) { red[wave] = s1; red[4 + wave] = s2; }
    __syncthreads();
    s1 = red[0] + red[1] + red[2] + red[3];
    s2 = red[4] + red[5] + red[6] + red[7];
    float mu = s1 * (1.f / 4096.f);
    float var = s2 * (1.f / 4096.f) - mu * mu;
    float rs = rsqrtf(var + 1e-5f);
    bf16* orow = out + (size_t)row * D;
#pragma unroll
    for (int j = 0; j < 4; ++j) {
        int base = (t + j * 256) * 4;
        float xs[4] = { v[j].x, v[j].y, v[j].z, v[j].w };
        bf16 o4[4];
#pragma unroll
        for (int c = 0; c < 4; ++c)
            o4[c] = __float2bfloat16((xs[c] - mu) * rs * gw[base + c] + gb[base + c]);
        *(int2*)(orow + base) = *(const int2*)o4;
    }
}

// ---------------------------------------------------------------- RoPE in-place on bf16 [rows, nheads*128]
__global__ void rope_kernel(bf16* __restrict__ x, int nheads, int seqlen, long total) {
    long idx = (long)blockIdx.x * 256 + threadIdx.x;
    if (idx >= total) return;
    int j = (int)(idx & 63);
    long t2 = idx >> 6;
    int h = (int)(t2 % nheads);
    long row = t2 / nheads;
    int pos = (int)(row % seqlen);
    float inv = exp2f(-(float)j * 0.20762050593046015f);  // log2(10000)/64
    float ang = (float)pos * inv;
    float s, c;
    sincosf(ang, &s, &c);
    bf16* p = x + row * ((long)nheads * 128) + (long)h * 128 + j;
    float x0 = __bfloat162float(p[0]);
    float x1 = __bfloat162float(p[64]);
    p[0]  = __float2bfloat16(x0 * c - x1 * s);
    p[64] = __float2bfloat16(x1 * c + x0 * s);
}

// ---------------------------------------------------------------- gemm_p: proven r3 pipelined GEMM (q/kv/o)
// BK=32, 3-buf LDS, trailing counted vmcnt, pair-swizzle (0 conflicts r3-r5), 2D XCD chunk.
template<int BM, int BN, int MODE, bool DUAL, int CM, int CN, int XN>
__global__ __launch_bounds__(512, 2) void gemm_p(
        const bf16* __restrict__ A, const bf16* __restrict__ W, const bf16* __restrict__ W2,
        void* __restrict__ Cout, void* __restrict__ Cout2, const void* __restrict__ aux,
        int M, int N, int K, int Nsplit)
{
    constexpr int MF = BM / 32;
    constexpr int NF = BN / 64;
    constexpr int ALD = BM / 128;
    constexpr int BLD = BN / 128;
    constexpr int SLD = ALD + BLD;
    __shared__ bf16 lds[3][(BM + BN) * 32];

    const int t = threadIdx.x;
    const int wid = t >> 6, lane = t & 63;
    const int lr = lane & 15, lg = lane >> 4;
    const int wr = wid >> 2, wc = wid & 3;
    const int bid = blockIdx.x;
    const int xcd = bid & 7, slot = bid >> 3;
    const int sm = slot / CN, sn = slot % CN;
    const int xm = xcd / XN, xn = xcd % XN;
    const int bm = (xm * CM + sm) * BM;
    const int bn = (xn * CN + sn) * BN;

    auto stage = [&](int tt, int buf) {
        const int k0 = tt * 32;
        char* ldsA = (char*)&lds[buf][0];
#pragma unroll
        for (int c = 0; c < ALD; ++c) {
            int Wb = (t + c * 512) * 16;
            int L = Wb ^ (((Wb >> 7) & 7) << 4);
            int row = L >> 6, colb = L & 63;
            gload_lds16(A + (size_t)(bm + row) * K + k0 + (colb >> 1), ldsA + Wb);
        }
        char* ldsB = (char*)&lds[buf][BM * 32];
#pragma unroll
        for (int c = 0; c < BLD; ++c) {
            int Wb = (t + c * 512) * 16;
            int L = Wb ^ (((Wb >> 7) & 7) << 4);
            int row = L >> 6, colb = L & 63;
            const bf16* src;
            if constexpr (DUAL) {
                int nr = bn + row;
                src = (nr >= Nsplit) ? W2 + (size_t)(nr - Nsplit) * K + k0 + (colb >> 1)
                                     : W  + (size_t)nr * K + k0 + (colb >> 1);
            } else {
                src = W + (size_t)(bn + row) * K + k0 + (colb >> 1);
            }
            gload_lds16(src, ldsB + Wb);
        }
    };

    const f32x4 zero4 = { 0.f, 0.f, 0.f, 0.f };
    f32x4 acc[MF][NF];
#pragma unroll
    for (int m = 0; m < MF; ++m)
#pragma unroll
        for (int n = 0; n < NF; ++n) acc[m][n] = zero4;

    const int T = K >> 5;
    stage(0, 0);
    stage(1, 1);
    if constexpr (SLD == 4) asm volatile("s_waitcnt vmcnt(4)" ::: "memory");
    else                    asm volatile("s_waitcnt vmcnt(3)" ::: "memory");
    __builtin_amdgcn_s_barrier();
    __builtin_amdgcn_sched_barrier(0);

    for (int tt = 0; tt < T; ++tt) {
        const int buf = tt % 3;
        bfv8 af[MF], bfr[NF];
#pragma unroll
        for (int m = 0; m < MF; ++m) {
            int row = wr * (BM / 2) + m * 16 + lr;
            int U = row * 64 + lg * 16;
            af[m] = *(const bfv8*)((const char*)&lds[buf][0] + (U ^ (((U >> 7) & 7) << 4)));
        }
#pragma unroll
        for (int n = 0; n < NF; ++n) {
            int row = wc * (BN / 4) + n * 16 + lr;
            int U = row * 64 + lg * 16;
            bfr[n] = *(const bfv8*)((const char*)&lds[buf][BM * 32] + (U ^ (((U >> 7) & 7) << 4)));
        }
        if (tt + 2 < T) stage(tt + 2, (tt + 2) % 3);
        __builtin_amdgcn_s_setprio(1);
#pragma unroll
        for (int m = 0; m < MF; ++m)
#pragma unroll
            for (int n = 0; n < NF; ++n)
                acc[m][n] = mfma16(af[m], bfr[n], acc[m][n]);
        __builtin_amdgcn_s_setprio(0);
        if (tt + 2 < T) {
            if constexpr (SLD == 4) asm volatile("s_waitcnt vmcnt(4)" ::: "memory");
            else                    asm volatile("s_waitcnt vmcnt(3)" ::: "memory");
        } else {
            asm volatile("s_waitcnt vmcnt(0)" ::: "memory");
        }
        __builtin_amdgcn_s_barrier();
        __builtin_amdgcn_sched_barrier(0);
    }

    const int r0 = bm + wr * (BM / 2), c0 = bn + wc * (BN / 4);
#pragma unroll
    for (int m = 0; m < MF; ++m)
#pragma unroll
        for (int n = 0; n < NF; ++n)
#pragma unroll
            for (int i = 0; i < 4; ++i) {
                int r = r0 + m * 16 + lg * 4 + i;
                int c = c0 + n * 16 + lr;
                float a = acc[m][n][i];
                if constexpr (DUAL) {
                    if (c < Nsplit) ((bf16*)Cout)[(size_t)r * Nsplit + c] = __float2bfloat16(a);
                    else ((bf16*)Cout2)[(size_t)r * (N - Nsplit) + (c - Nsplit)] = __float2bfloat16(a);
                } else {
                    size_t idx = (size_t)r * N + c;
                    if constexpr (MODE == 0) {
                        ((bf16*)Cout)[idx] = __float2bfloat16(a);
                    } else if constexpr (MODE == 1) {
                        a = a / (1.f + expf(-a));
                        ((bf16*)Cout)[idx] = __float2bfloat16(a);
                    } else if constexpr (MODE == 2) {
                        a *= __bfloat162float(((const bf16*)aux)[idx]);
                        ((bf16*)Cout)[idx] = __float2bfloat16(a);
                    } else {
                        ((float*)Cout)[idx] = a + ((const float*)aux)[idx];
                    }
                }
            }
}

// ---------------------------------------------------------------- gemm8: 8-phase pipelined GEMM, BK=64
// Event-stream schedule; r6 fixed the LDS WAR (A/B halves die only after BOTH MH/NH read
// phases); r7 fixes the last-iteration RAW: at ph4 with le=false only 8 loads are
// outstanding (o.B + o.A), so vmcnt(4) left o.A in flight while ph5 ds_reads buf1.A.
// GATE(le) drains to vmcnt(0) in the last iteration (steady state unchanged at vmcnt(4)).
// BIG (BN=256, 2 bufs): ph1:o.Ah0 ph2:o.Ah1 ph3:e2.Bh0 ph4:e2.Bh1+GATE(le) ph5:e2.Ah0
//   ph6:e2.Ah1 ph7:o2.Bh0 ph8:o2.Bh1+GATE(le). Steady: 12 loads out, vmcnt(4) retires
//   the gated tile's 4 events. T even => le implies lo.
// SMALL (BN=128, 3 bufs): stage targets are FULLY dead buffers:
//   ph_a:{e2.Ah0,e2.B}->bN ph_b:{e2.Ah1}+GATE(le) vmcnt(6) ph_c:{o2.*}->bE
//   ph_d:{o2.Ah1}+GATE(lo) vmcnt(6). Audited clean (last iter drains via GATE(false)).
// sched_barrier(0) only after lgkmcnt(0) (rule 18). Pair-swizzle on 128B rows.
template<int BN, int MODE, bool DUAL, int CM, int CN, int XN>
__global__ __launch_bounds__(512, 1) void gemm8(
        const bf16* __restrict__ A, const bf16* __restrict__ W, const bf16* __restrict__ W2,
        void* __restrict__ Cout, void* __restrict__ Cout2, const void* __restrict__ aux,
        int M, int N, int K, int Nsplit)
{
    constexpr bool BIG = (BN == 256);
    constexpr int NBUF = BIG ? 2 : 3;
    constexpr int ABY = 32768;            // A tile 256 rows x 128B
    constexpr int BBY = BN * 128;
    constexpr int TBY = ABY + BBY;
    __shared__ alignas(16) char lds8[NBUF * TBY];

    const int t = threadIdx.x;
    const int wid = t >> 6, lane = t & 63;
    const int lr = lane & 15, lg = lane >> 4;
    const int wr = wid >> 2, wc = wid & 3;
    const int bid = blockIdx.x;
    const int xcd = bid & 7, slot = bid >> 3;
    const int sm = slot / CN, sn = slot % CN;
    const int xm = xcd / XN, xn = xcd % XN;
    const int bm = (xm * CM + sm) * 256;
    const int bn = (xn * CN + sn) * BN;

    auto stA = [&](int kt, int h, int buf) {      // A rows h*128..h*128+127 (2 loads)
#pragma unroll
        for (int c = 0; c < 2; ++c) {
            int Wb = (t + c * 512) * 16;
            int L = Wb ^ (((Wb >> 7) & 7) << 4);
            gload_lds16(A + (size_t)(bm + h * 128 + (L >> 7)) * K + kt * 64 + ((L & 127) >> 1),
                        lds8 + buf * TBY + h * 16384 + Wb);
        }
    };
    auto stB = [&](int kt, int h, int buf) {
#pragma unroll
        for (int c = 0; c < 2; ++c) {
            int Wb = (t + c * 512) * 16;
            int L = Wb ^ (((Wb >> 7) & 7) << 4);
            int nr = bn + h * 128 + (L >> 7);
            const bf16* src;
            if constexpr (DUAL) {
                src = (nr >= Nsplit) ? W2 + (size_t)(nr - Nsplit) * K + kt * 64 + ((L & 127) >> 1)
                                     : W  + (size_t)nr * K + kt * 64 + ((L & 127) >> 1);
            } else {
                src = W + (size_t)nr * K + kt * 64 + ((L & 127) >> 1);
            }
            gload_lds16(src, lds8 + buf * TBY + ABY + h * 16384 + Wb);
        }
    };

    const f32x4 zero4 = { 0.f, 0.f, 0.f, 0.f };
    f32x4 acc[8][BIG ? 4 : 2];
#pragma unroll
    for (int m = 0; m < 8; ++m)
#pragma unroll
        for (int n = 0; n < (BIG ? 4 : 2); ++n) acc[m][n] = zero4;

    bfv8 af[4][2], bfr[BIG ? 2 : 1][2][2];

#define LOADA(BUF, MH) do {                                                   \
    const char* _ba = lds8 + (BUF) * TBY;                                     \
    _Pragma("unroll") for (int m = 0; m < 4; ++m)                             \
    _Pragma("unroll") for (int ks = 0; ks < 2; ++ks) {                        \
        int row = wr * 128 + (MH) * 64 + m * 16 + lr;                         \
        int U = row * 128 + ks * 64 + lg * 16;                                \
        af[m][ks] = *(const bfv8*)(_ba + (U ^ ((row & 7) << 4)));             \
    } } while (0)

#define LOADB(BUF, NH) do {                                                   \
    const char* _bb = lds8 + (BUF) * TBY + ABY;                               \
    _Pragma("unroll") for (int n = 0; n < 2; ++n)                             \
    _Pragma("unroll") for (int ks = 0; ks < 2; ++ks) {                        \
        int row = wc * (BN / 4) + (NH) * (BN / 8) + n * 16 + lr;              \
        int U = row * 128 + ks * 64 + lg * 16;                                \
        bfr[NH][n][ks] = *(const bfv8*)(_bb + (U ^ ((row & 7) << 4)));        \
    } } while (0)

#define MFMAQ(MH, NH) do {                                                    \
    _Pragma("unroll") for (int m = 0; m < 4; ++m)                             \
    _Pragma("unroll") for (int n = 0; n < 2; ++n) {                           \
        acc[(MH)*4+m][(NH)*2+n] = mfma16(af[m][0], bfr[NH][n][0], acc[(MH)*4+m][(NH)*2+n]); \
        acc[(MH)*4+m][(NH)*2+n] = mfma16(af[m][1], bfr[NH][n][1], acc[(MH)*4+m][(NH)*2+n]); \
    } } while (0)

#define PH_TOP() do { __builtin_amdgcn_s_barrier();                           \
    asm volatile("s_waitcnt lgkmcnt(0)" ::: "memory");                        \
    __builtin_amdgcn_sched_barrier(0);                                        \
    __builtin_amdgcn_s_setprio(1); } while (0)

#define PH_END() do { __builtin_amdgcn_s_setprio(0);                          \
    __builtin_amdgcn_s_barrier(); } while (0)

#define GATE(LIVE) do { __builtin_amdgcn_s_setprio(0);                        \
    if (LIVE) { if constexpr (BIG) asm volatile("s_waitcnt vmcnt(4)" ::: "memory"); \
                else               asm volatile("s_waitcnt vmcnt(6)" ::: "memory"); } \
    else      asm volatile("s_waitcnt vmcnt(0)" ::: "memory");                \
    __builtin_amdgcn_s_barrier(); } while (0)

    const int T = K >> 6;
    const int T2 = T >> 1;

    if constexpr (BIG) {
        // prologue: t0 full; t1 {Bh0,Bh1}. 12 loads; vmcnt(4) retires t0's 8.
        stA(0, 0, 0); stA(0, 1, 0); stB(0, 0, 0); stB(0, 1, 0);
        stB(1, 0, 1); stB(1, 1, 1);
        asm volatile("s_waitcnt vmcnt(4)" ::: "memory");
        __builtin_amdgcn_s_barrier();

        for (int tt = 0; tt < T2; ++tt) {
            const int o = 2 * tt + 1, e2 = 2 * tt + 2, o2 = 2 * tt + 3;
            const bool le = (e2 < T), lo = (o2 < T);
            // ---- tile e (buf0)
            LOADA(0, 0); LOADB(0, 0); stA(o, 0, 1);          // ph1 + o.Ah0 (buf1.A dead since prev ph7)
            PH_TOP(); MFMAQ(0, 0); PH_END();
            LOADB(0, 1); stA(o, 1, 1);                       // ph2 + o.Ah1
            PH_TOP(); MFMAQ(0, 1); PH_END();
            LOADA(0, 1); if (le) stB(e2, 0, 0);              // ph3 + e2.Bh0 (buf0.B dead after ph2)
            PH_TOP(); MFMAQ(1, 1); PH_END();
            if (le) stB(e2, 1, 0);                           // ph4 + e2.Bh1
            PH_TOP(); MFMAQ(1, 0); GATE(le);                 // r7 fix: drain fully when !le
            // ---- tile o (buf1)
            LOADA(1, 0); LOADB(1, 0); if (le) stA(e2, 0, 0); // ph5 + e2.Ah0 (buf0.A dead after ph3)
            PH_TOP(); MFMAQ(0, 0); PH_END();
            LOADB(1, 1); if (le) stA(e2, 1, 0);              // ph6 + e2.Ah1
            PH_TOP(); MFMAQ(0, 1); PH_END();
            LOADA(1, 1); if (lo) stB(o2, 0, 1);              // ph7 + o2.Bh0 (buf1.B dead after ph6)
            PH_TOP(); MFMAQ(1, 1); PH_END();
            if (lo) stB(o2, 1, 1);                           // ph8 + o2.Bh1
            PH_TOP(); MFMAQ(1, 0); GATE(le);                 // tile e2 complete (T even => le implies lo)
        }
    } else {
        // prologue: t0 -> buf0, t1 -> buf1 (3 events each); vmcnt(6) retires t0's 6.
        stA(0, 0, 0); stB(0, 0, 0); stA(0, 1, 0);
        stA(1, 0, 1); stB(1, 0, 1); stA(1, 1, 1);
        asm volatile("s_waitcnt vmcnt(6)" ::: "memory");
        __builtin_amdgcn_s_barrier();

        int bE = 0, bO = 1, bN = 2;
        for (int tt = 0; tt < T2; ++tt) {
            const int e2 = 2 * tt + 2, o2 = 2 * tt + 3;
            const bool le = (e2 < T), lo = (o2 < T);
            // ---- tile e (buf bE); stage e+2 -> bN (bN = tile e-1, fully dead)
            LOADA(bE, 0); LOADB(bE, 0); if (le) { stA(e2, 0, bN); stB(e2, 0, bN); }
            PH_TOP(); MFMAQ(0, 0); PH_END();
            LOADA(bE, 1); if (le) stA(e2, 1, bN);
            PH_TOP(); MFMAQ(1, 0); GATE(le);
            // ---- tile o (buf bO); stage o+2 -> bE (fully read at ph_a+ph_b)
            LOADA(bO, 0); LOADB(bO, 0); if (lo) { stA(o2, 0, bE); stB(o2, 0, bE); }
            PH_TOP(); MFMAQ(0, 0); PH_END();
            LOADA(bO, 1); if (lo) stA(o2, 1, bE);
            PH_TOP(); MFMAQ(1, 0); GATE(lo);
            int nE = bN, nO = bE, nN = bO;
            bE = nE; bO = nO; bN = nN;
        }
    }

#undef LOADA
#undef LOADB
#undef MFMAQ
#undef PH_TOP
#undef PH_END
#undef GATE

    const int r0 = bm + wr * 128, c0 = bn + wc * (BN / 4);
#pragma unroll
    for (int mg = 0; mg < 8; ++mg)
#pragma unroll
        for (int ng = 0; ng < (BIG ? 4 : 2); ++ng)
#pragma unroll
            for (int i = 0; i < 4; ++i) {
                int r = r0 + mg * 16 + lg * 4 + i;
                int c = c0 + ng * 16 + lr;
                float a = acc[mg][ng][i];
                if constexpr (DUAL) {
                    if (c < Nsplit) ((bf16*)Cout)[(size_t)r * Nsplit + c] = __float2bfloat16(a);
                    else ((bf16*)Cout2)[(size_t)r * (N - Nsplit) + (c - Nsplit)] = __float2bfloat16(a);
                } else {
                    size_t idx = (size_t)r * N + c;
                    if constexpr (MODE == 0) {
                        ((bf16*)Cout)[idx] = __float2bfloat16(a);
                    } else if constexpr (MODE == 1) {
                        a = a / (1.f + expf(-a));
                        ((bf16*)Cout)[idx] = __float2bfloat16(a);
                    } else if constexpr (MODE == 2) {
                        a *= __bfloat162float(((const bf16*)aux)[idx]);
                        ((bf16*)Cout)[idx] = __float2bfloat16(a);
                    } else {
                        ((float*)Cout)[idx] = a + ((const float*)aux)[idx];
                    }
                }
            }
}

// ---------------------------------------------------------------- V transpose: vb[(b*2048+kv)][1024] -> vt[(b*1024+col)][2048]
__global__ void transpose_v(const bf16* __restrict__ vb, bf16* __restrict__ vt) {
    __shared__ bf16 tile[64][68];
    int kv0 = blockIdx.x * 64, c0 = blockIdx.y * 64, b = blockIdx.z;
    int t = threadIdx.x;
    int cr = t & 15, rr = t >> 4;
#pragma unroll
    for (int j = 0; j < 4; ++j) {
        int r = rr + j * 16;
        *(int2*)&tile[r][cr * 4] = *(const int2*)&vb[(size_t)(b * 2048 + kv0 + r) * 1024 + c0 + cr * 4];
    }
    __syncthreads();
#pragma unroll
    for (int j = 0; j < 4; ++j) {
        int cc = rr + j * 16;
        bf16 tmp[4];
#pragma unroll
        for (int q = 0; q < 4; ++q) tmp[q] = tile[cr * 4 + q][cc];
        *(int2*)&vt[(size_t)(b * 1024 + c0 + cc) * 2048 + kv0 + cr * 4] = *(const int2*)tmp;
    }
}

// ---------------------------------------------------------------- flash attention v2 (GQA 32q/8kv, HD=128)
__global__ __launch_bounds__(256) void attn_kernel(
    const bf16* __restrict__ Q, const bf16* __restrict__ Kb, const bf16* __restrict__ Vt,
    const float* __restrict__ mask, bf16* __restrict__ O)
{
    const int QL_ = 1024, KVL_ = 2048;
    const float scale = 0.08838834764831845f;  // 1/sqrt(128)
    int qt = blockIdx.x, h = blockIdx.y, b = blockIdx.z;
    int t = threadIdx.x, wave = t >> 6, lane = t & 63;
    int lr = lane & 15, lg = lane >> 4;
    int g = h >> 2;
    __shared__ bf16 Ksm[64 * 128];
    __shared__ bf16 Vsm[128 * 64];
    __shared__ bf16 Psm[4][16 * 72];
    int q0 = qt * 64 + wave * 16;

    const bf16* qptr = Q + (size_t)(b * QL_ + q0 + lr) * 4096 + h * 128;
    bfv8 qf[4];
#pragma unroll
    for (int kc = 0; kc < 4; ++kc) qf[kc] = *(const bfv8*)(qptr + kc * 32 + lg * 8);

    const f32x4 zero4 = { 0.f, 0.f, 0.f, 0.f };
    f32x4 accO[8];
#pragma unroll
    for (int dt = 0; dt < 8; ++dt) accO[dt] = zero4;
    float mrow[4] = { -1e30f, -1e30f, -1e30f, -1e30f };
    float lrow[4] = { 0.f, 0.f, 0.f, 0.f };

    for (int kv0 = 0; kv0 < KVL_; kv0 += 64) {
#pragma unroll
        for (int p2 = 0; p2 < 4; ++p2) {
            int Wb = (p2 * 256 + t) * 16;
            int row = Wb >> 8;
            int col = ((Wb & 255) ^ ((row & 7) << 4)) >> 1;
            gload_lds16(Kb + (size_t)(b * KVL_ + kv0 + row) * 1024 + g * 128 + col,
                        (char*)Ksm + Wb);
        }
#pragma unroll
        for (int p2 = 0; p2 < 4; ++p2) {
            int Wb = (p2 * 256 + t) * 16;
            int row = Wb >> 7;
            int col = ((Wb & 127) ^ ((row & 7) << 4)) >> 1;
            gload_lds16(Vt + (size_t)(b * 1024 + g * 128 + row) * 2048 + kv0 + col,
                        (char*)Vsm + Wb);
        }
        __syncthreads();

        f32x4 s[4];
#pragma unroll
        for (int ct = 0; ct < 4; ++ct) {
            s[ct] = zero4;
#pragma unroll
            for (int kc = 0; kc < 4; ++kc) {
                int row = ct * 16 + lr;
                int U = row * 256 + kc * 64 + lg * 16;
                bfv8 kf = *(const bfv8*)((const char*)Ksm + (U ^ ((row & 7) << 4)));
                s[ct] = mfma16(qf[kc], kf, s[ct]);
            }
            float mv = mask[(size_t)b * KVL_ + kv0 + ct * 16 + lr];
            mv = (mv != 0.f) ? 1.f : 0.f;
#pragma unroll
            for (int i = 0; i < 4; ++i) s[ct][i] = s[ct][i] * scale + mv;
        }

        float rmx[4], mnew[4], corr[4], psum[4];
#pragma unroll
        for (int i = 0; i < 4; ++i) {
            rmx[i] = fmaxf(fmaxf(s[0][i], s[1][i]), fmaxf(s[2][i], s[3][i]));
#pragma unroll
            for (int d = 1; d < 16; d <<= 1) rmx[i] = fmaxf(rmx[i], __shfl_xor(rmx[i], d));
            mnew[i] = fmaxf(mrow[i], rmx[i]);
            corr[i] = expf(mrow[i] - mnew[i]);
            psum[i] = 0.f;
        }
#pragma unroll
        for (int ct = 0; ct < 4; ++ct)
#pragma unroll
            for (int i = 0; i < 4; ++i) {
                float pv = expf(s[ct][i] - mnew[i]);
                psum[i] += pv;
                Psm[wave][(lg * 4 + i) * 72 + ct * 16 + lr] = __float2bfloat16(pv);
            }
#pragma unroll
        for (int i = 0; i < 4; ++i) {
#pragma unroll
            for (int d = 1; d < 16; d <<= 1) psum[i] += __shfl_xor(psum[i], d);
            lrow[i] = lrow[i] * corr[i] + psum[i];
            mrow[i] = mnew[i];
        }
#pragma unroll
        for (int dt = 0; dt < 8; ++dt)
#pragma unroll
            for (int i = 0; i < 4; ++i) accO[dt][i] *= corr[i];
        __syncthreads();

        bfv8 pf0 = *(const bfv8*)&Psm[wave][lr * 72 + 0 * 32 + lg * 8];
        bfv8 pf1 = *(const bfv8*)&Psm[wave][lr * 72 + 1 * 32 + lg * 8];
#pragma unroll
        for (int dt = 0; dt < 8; ++dt) {
            int row = dt * 16 + lr;
            int U0 = row * 128 + 0 * 64 + lg * 16;
            int U1 = row * 128 + 1 * 64 + lg * 16;
            bfv8 vf0 = *(const bfv8*)((const char*)Vsm + (U0 ^ ((row & 7) << 4)));
            bfv8 vf1 = *(const bfv8*)((const char*)Vsm + (U1 ^ ((row & 7) << 4)));
            accO[dt] = mfma16(pf0, vf0, accO[dt]);
            accO[dt] = mfma16(pf1, vf1, accO[dt]);
        }
        __syncthreads();
    }

    float invl[4];
#pragma unroll
    for (int i = 0; i < 4; ++i) invl[i] = 1.f / lrow[i];
#pragma unroll
    for (int dt = 0; dt < 8; ++dt)
#pragma unroll
        for (int i = 0; i < 4; ++i)
            O[(size_t)(b * QL_ + q0 + lg * 4 + i) * 4096 + h * 128 + dt * 16 + lr] =
                __float2bfloat16(accO[dt][i] * invl[i]);
}

// ---------------------------------------------------------------- launch
extern "C" void kernel_launch(void* const* d_in, const int* in_sizes, int n_in,
                              void* d_out, int out_size, void* d_ws, size_t ws_size,
                              hipStream_t stream) {
    const float* hidden = (const float*)d_in[0];
    const float* enc    = (const float*)d_in[1];
    const float* mask   = (const float*)d_in[2];
    const float* ln1w   = (const float*)d_in[3];
    const float* ln1b   = (const float*)d_in[4];
    const float* qw     = (const float*)d_in[5];
    const float* kw     = (const float*)d_in[6];
    const float* vw     = (const float*)d_in[7];
    const float* ow     = (const float*)d_in[8];
    const float* ln2w   = (const float*)d_in[9];
    const float* ln2b   = (const float*)d_in[10];
    const float* gatew  = (const float*)d_in[11];
    const float* upw    = (const float*)d_in[12];
    const float* downw  = (const float*)d_in[13];
    float* out = (float*)d_out;

    char* ws = (char*)d_ws;
    bf16*  wbuf  = (bf16*)(ws);
    bf16*  wbuf2 = (bf16*)(ws + 8388608);
    bf16*  h1    = (bf16*)(ws + 134217728);
    bf16*  encb  = (bf16*)(ws + 150994944);
    bf16*  qb    = (bf16*)(ws + 184549376);
    bf16*  kb    = (bf16*)(ws + 201326592);
    bf16*  vb    = (bf16*)(ws + 209715200);
    bf16*  attno = (bf16*)(ws + 218103808);
    float* h2    = (float*)(ws + 234881024);
    bf16*  vt    = (bf16*)(ws + 234881024);
    bf16*  h2n   = (bf16*)(ws + 268435456);
    bf16*  g1    = (bf16*)(ws + 285212672);

    auto cvt = [&](const float* src, bf16* dst, long n) {
        cvt_kernel<<<(int)(n / 2048), 256, 0, stream>>>(src, dst, n / 8);
    };

    // encoder hidden -> bf16; LN1(hidden) -> bf16
    cvt(enc, encb, 16777216L);
    layernorm_kernel<<<2048, 256, 0, stream>>>(hidden, ln1w, ln1b, h1);

    // Q = h1 x qw^T [2048, 4096] (proven gemm_p)
    cvt(qw, wbuf, 16777216L);
    gemm_p<128, 256, 0, false, 8, 4, 4><<<256, 512, 0, stream>>>(
        h1, wbuf, nullptr, qb, nullptr, nullptr, 2048, 4096, 4096, 0);
    rope_kernel<<<16384, 256, 0, stream>>>(qb, 32, 1024, 2048L * 32 * 64);

    // K,V fused [4096, 2048] (proven gemm_p DUAL)
    cvt(kw, wbuf, 4194304L);
    cvt(vw, wbuf2, 4194304L);
    gemm_p<128, 256, 0, true, 8, 4, 2><<<256, 512, 0, stream>>>(
        encb, wbuf, wbuf2, kb, vb, nullptr, 4096, 2048, 4096, 1024);
    rope_kernel<<<8192, 256, 0, stream>>>(kb, 8, 2048, 4096L * 8 * 64);
    transpose_v<<<dim3(32, 16, 2), 256, 0, stream>>>(vb, vt);

    // attention
    attn_kernel<<<dim3(16, 32, 2), 256, 0, stream>>>(qb, kb, vt, mask, attno);

    // h2 = hidden + attno x ow^T (proven gemm_p)
    cvt(ow, wbuf, 16777216L);
    gemm_p<128, 256, 3, false, 8, 4, 4><<<256, 512, 0, stream>>>(
        attno, wbuf, nullptr, h2, nullptr, hidden, 2048, 4096, 4096, 0);

    // LN2 -> bf16
    layernorm_kernel<<<2048, 256, 0, stream>>>(h2, ln2w, ln2b, h2n);

    // g1 = silu(h2n x gatew^T); g1 *= h2n x upw^T  (8-phase BIG, r7 gate fix)
    cvt(gatew, wbuf, 67108864L);
    gemm8<256, 1, false, 8, 8, 8><<<512, 512, 0, stream>>>(
        h2n, wbuf, nullptr, g1, nullptr, nullptr, 2048, 16384, 4096, 0);
    cvt(upw, wbuf, 67108864L);
    gemm8<256, 2, false, 8, 8, 8><<<512, 512, 0, stream>>>(
        h2n, wbuf, nullptr, g1, nullptr, g1, 2048, 16384, 4096, 0);

    // out = h2 + g1 x downw^T (8-phase SMALL, 3-buf)
    cvt(downw, wbuf, 67108864L);
    gemm8<128, 3, false, 8, 4, 8><<<256, 512, 0, stream>>>(
        g1, wbuf, nullptr, out, nullptr, h2, 2048, 4096, 16384, 0);
}